// Round 19
// baseline (599.913 us; speedup 1.0000x reference)
//
#include <hip/hip_runtime.h>
#include <cmath>

#define NS 64
#define NN 128
#define NT 1000
#define CH 8                                // steps per obuf half-buffer
#define NNP 129                             // padded flush-row stride (bank-free)
#define WROWS 130                           // 128 rows of w + 2 zero rows
#define WL_DW (WROWS * NN)                  // 16640
#define OB_HALF (CH * 3 * NNP)              // 3096 dwords per half-buffer
#define OBUF_DW (2 * OB_HALF)               // 6192
#define LDS_BYTES ((WL_DW + OBUF_DW) * 4 + 32)   // 91360

// == npy_logaddexpf(x, 0), branch-free but bit-identical:
//   x>0: fmax=x, |x|=x  -> x + log1p(exp(-x)) ; x<0: 0 + log1p(exp(x)) ; x==0 -> LOGE2
__device__ __forceinline__ float softplus_np(float x) {
    float r = fmaxf(x, 0.0f) + log1pf(expf(-fabsf(x)));
    return (x == 0.0f) ? 0.693147180559945309f : r;
}

// Barrier WITHOUT the compiler's vmcnt(0) drain: LDS-visibility only.
__device__ __forceinline__ void sync_lds() {
    __builtin_amdgcn_sched_barrier(0);
    asm volatile("s_waitcnt lgkmcnt(0)" ::: "memory");
    __builtin_amdgcn_s_barrier();
    __builtin_amdgcn_sched_barrier(0);
}

__global__ __launch_bounds__(192) void snn_scan_kernel(
    const float* __restrict__ w,
    const float* __restrict__ ic,
    const float* __restrict__ v0,
    const float* __restrict__ i0,
    const float* __restrict__ s0,
    const float* __restrict__ mu,
    const float* __restrict__ sigma,
    const float* __restrict__ noise,      // [T, S, N, 2]
    const float* __restrict__ exp_draws,  // [T, S, N]
    float* __restrict__ out)              // [S, N, T, 3]
{
    #pragma clang fp contract(off)
    extern __shared__ float smem[];
    float* wl   = smem;                   // [130][128]: w rows + 2 zero rows
    float* obuf = smem + WL_DW;           // [2][CH*3][NNP] output staging (padded)
    unsigned long long* mslot =           // [2 parity][2 waves] spike masks
        (unsigned long long*)(smem + WL_DW + OBUF_DW);

    const int samp = blockIdx.x;
    const int tid  = threadIdx.x;
    const int wid  = tid >> 6;            // waves 0,1 = compute; wave 2 = flush
    const int l    = tid & 63;
    const int n    = (wid << 6) | l;      // neuron (waves 0,1): 1 neuron/lane

    if (tid < 128) {                      // stage w + zero rows (one-time)
        const float4* src = (const float4*)w;
        float4* dst = (float4*)wl;
        #pragma unroll
        for (int it = 0; it < 32; ++it)
            dst[it * 128 + tid] = src[it * 128 + tid];
        ((float2*)(wl + NN * NN))[tid] = make_float2(0.0f, 0.0f);
    }

    const float SQDT  = sqrtf(0.01f);     // 0x3DCCCCCD == np.sqrt(float32(0.01))
    const float DTf   = 0.01f;
    const float LOGE2 = 0.693147180559945309f;

    float* outb = out + (size_t)samp * NN * NT * 3;

    float mu1 = 0.f, negmu2 = 0.f, g00 = 0.f, g01 = 0.f, g10 = 0.f, g11 = 0.f;
    float icn = 0.f, v_ = 0.f, s_ = 0.f, sp = 0.f;
    float it_prev = 0.f;                  // drift-only i of prev step (pre-coupling)
    float q1v = 0.f, q2v = 0.f, q3v = 0.f, q4v = 0.f;   // deferred coupling reads
    float afull = 0.f;                    // pre-resolved sum (bootstrap / >=5 case)
    bool  fullf = true;
    float2 nb0 = {}, nb1 = {}, nb2 = {}, nb3 = {}, nb4 = {}, nb5 = {}, nb6 = {}, nb7 = {};
    float  eb0 = 0, eb1 = 0, eb2 = 0, eb3 = 0, eb4 = 0, eb5 = 0, eb6 = 0, eb7 = 0;

    const float* nzb = noise + (size_t)samp * (NN * 2) + n * 2;   // + t*NS*NN*2
    const float* edb = exp_draws + (size_t)samp * NN + n;         // + t*NS*NN

    if (wid < 2) {
        __builtin_amdgcn_s_setprio(1);    // compute waves own the critical path
        mu1 = mu[0]; negmu2 = -mu[1];
        g00 = sigma[0]; g01 = sigma[1]; g10 = sigma[2]; g11 = sigma[3];
        icn = ic[n];
        v_ = v0[samp * NN + n];
        it_prev = i0[samp * NN + n];      // step 0: i = i0 + 0.0 (afull=0, i0>0)
        s_ = s0[samp * NN + n];
        sp = softplus_np(v_);
        afull = 0.0f; fullf = true;
        nb0 = *(const float2*)(nzb + 0ull * (NS * NN * 2)); eb0 = edb[0ull * (NS * NN)];
        nb1 = *(const float2*)(nzb + 1ull * (NS * NN * 2)); eb1 = edb[1ull * (NS * NN)];
        nb2 = *(const float2*)(nzb + 2ull * (NS * NN * 2)); eb2 = edb[2ull * (NS * NN)];
        nb3 = *(const float2*)(nzb + 3ull * (NS * NN * 2)); eb3 = edb[3ull * (NS * NN)];
        nb4 = *(const float2*)(nzb + 4ull * (NS * NN * 2)); eb4 = edb[4ull * (NS * NN)];
        nb5 = *(const float2*)(nzb + 5ull * (NS * NN * 2)); eb5 = edb[5ull * (NS * NN)];
        nb6 = *(const float2*)(nzb + 6ull * (NS * NN * 2)); eb6 = edb[6ull * (NS * NN)];
        nb7 = *(const float2*)(nzb + 7ull * (NS * NN * 2)); eb7 = edb[7ull * (NS * NN)];
    }
    sync_lds();                           // w + zero rows visible

    if (wid < 2) {
        // ---------------- compute waves ----------------
        auto STEP = [&](int k, int blk, float2& nb, float& eb) {
            #pragma clang fp contract(off)
            const int t = blk * CH + k;
            // --- top: s-chain + spike-mask publish (independent of coupling)
            s_ = s_ + DTf * sp;
            const bool kk = (s_ >= 0.0f);
            const unsigned long long mym = __ballot(kk);
            if (l == 0) mslot[(k & 1) * 2 + wid] = mym;
            // --- deferred coupling resolve of step t-1 (q regs read LAST step:
            //     latency hidden under the whole previous step body + barrier)
            float a;
            if (fullf) a = afull;
            else { a = q1v; a += q2v; a += q3v; a += q4v; }   // ascending order
            const float i_cur = it_prev + a;                  // i(t-1), bit-identical
            {   // i-plane obuf write of step t-1 (t=0 -> dummy half1/slot7,
                // overwritten by step 15's write before any flush reads it)
                const int tm1 = (t == 0) ? 15 : (t - 1);
                obuf[((tm1 >> 3) & 1) * OB_HALF + ((tm1 & 7) * 3 + 1) * NNP + n] = i_cur;
            }
            sync_lds();
            // --- post-barrier: drift + noise overlap the mask-read latency
            const float2 nz = nb;
            const float  ed = eb;
            const int tp = (t + 8) < NT ? (t + 8) : NT - 1;   // clamped prefetch
            nb = *(const float2*)(nzb + (size_t)tp * (NS * NN * 2));
            eb = edb[(size_t)tp * (NS * NN)];

            const float dw0 = nz.x * SQDT, dw1 = nz.y * SQDT;
            const float nv = (dw0 * g00) + (dw1 * g01);
            const float ni = (dw0 * g10) + (dw1 * g11);
            const float tt = (i_cur + icn) - v_;
            const float vt = (v_ + DTf * (mu1 * tt)) + nv;
            const float it = (i_cur + DTf * (negmu2 * i_cur)) + ni;
            const float spv = softplus_np(vt);   // speculative next-step intensity

            unsigned long long m0 = mslot[(k & 1) * 2 + 0];   // neurons 0..63
            unsigned long long m1 = mslot[(k & 1) * 2 + 1];   // neurons 64..127

            v_ = kk ? 0.0f : vt;
            s_ = kk ? -ed : s_;
            sp = kk ? LOGE2 : spv;

            {   // v,s-plane obuf writes for step t (i-plane comes next step)
                float* row = obuf + (blk & 1) * OB_HALF + (k * 3) * NNP + n;
                row[0 * NNP] = v_;
                row[2 * NNP] = s_;
            }

            // --- extraction + q-read ISSUE for step t (consumed next step top)
            if (m0 | m1) {
                auto ext1 = [&]() -> int {    // ascending order: drain m0 then m1
                    const bool u0 = (m0 != 0);
                    const unsigned long long m = u0 ? m0 : m1;
                    const int b = m ? (int)__builtin_ctzll(m) : 99;
                    const int r = (b == 99) ? 128 : ((u0 ? 0 : 64) + b);
                    const unsigned long long m0n = m0 & (m0 - 1);
                    const unsigned long long m1n = m1 & (m1 - 1);
                    m0 = u0 ? m0n : m0;
                    m1 = u0 ? m1 : m1n;
                    return r;             // empty -> zero row 128 (+0.0 exact)
                };
                const int r1 = ext1(); const int r2 = ext1();
                const int r3 = ext1(); const int r4 = ext1();
                q1v = wl[r1 * NN + n];    // 4 independent ds_read_b32, carried
                q2v = wl[r2 * NN + n];
                q3v = wl[r3 * NN + n];
                q4v = wl[r4 * NN + n];
                if (m0 | m1) {            // >=5 spikes: rare, resolve fully inline
                    float a2 = q1v; a2 += q2v; a2 += q3v; a2 += q4v;
                    #pragma clang loop unroll(disable)
                    do {
                        const int r = ext1();
                        a2 += wl[r * NN + n];
                    } while (m0 | m1);
                    afull = a2; fullf = true;
                } else {
                    fullf = false;
                }
            } else {
                afull = 0.0f; fullf = true;   // empty step: exact +0.0
            }
            it_prev = it;
        };

        #pragma clang loop unroll(disable)
        for (int blk = 0; blk < NT / CH; ++blk) {
            STEP(0, blk, nb0, eb0);
            STEP(1, blk, nb1, eb1);
            STEP(2, blk, nb2, eb2);
            STEP(3, blk, nb3, eb3);
            STEP(4, blk, nb4, eb4);
            STEP(5, blk, nb5, eb5);
            STEP(6, blk, nb6, eb6);
            STEP(7, blk, nb7, eb7);
        }

        // epilogue: resolve step 999's coupling + i-plane write (half 0, slot 7)
        {
            float a;
            if (fullf) a = afull;
            else { a = q1v; a += q2v; a += q3v; a += q4v; }
            const float ifin = it_prev + a;
            obuf[0 * OB_HALF + (7 * 3 + 1) * NNP + n] = ifin;
        }
    } else {
        // ---------------- flush wave ----------------
        // flush(block b) runs during block b+1, slots 1..6 (4 j-iters each);
        // i(8b+7) is written at slot-0-top of block b+1, drained at B(slot 1).
        auto flush4 = [&](int h, int tb0, int slot) {
            const float* ob2 = obuf + h * OB_HALF;
            #pragma unroll
            for (int j = 4 * (slot - 1); j < 4 * slot; ++j) {
                const int f = j * 64 + l;        // float2 slot 0..1535
                const int nn2 = f / 12;          // neuron
                const int da = 2 * (f - nn2 * 12);
                const float x = ob2[(da    ) * NNP + nn2];
                const float y = ob2[(da + 1) * NNP + nn2];
                *(float2*)(outb + (size_t)nn2 * (NT * 3) + (size_t)tb0 * 3 + da) =
                    make_float2(x, y);
            }
        };
        #pragma clang loop unroll(disable)
        for (int blk = 0; blk < NT / CH; ++blk) {
            #pragma clang loop unroll(disable)
            for (int k = 0; k < CH; ++k) {
                sync_lds();               // match compute waves' per-step barrier
                if (blk > 0 && k >= 1 && k <= 6)
                    flush4((blk - 1) & 1, (blk - 1) * CH, k);
            }
        }
    }

    // final barrier: step 999's i-plane write (epilogue) + last v,s writes
    // must be visible before the tail flush of block 124 (half 0)
    sync_lds();
    if (wid == 2) {
        const float* ob2 = obuf + 0 * OB_HALF;   // block 124 -> half 124&1 = 0
        #pragma unroll
        for (int j = 0; j < 24; ++j) {
            const int f = j * 64 + l;
            const int nn2 = f / 12;
            const int da = 2 * (f - nn2 * 12);
            const float x = ob2[(da    ) * NNP + nn2];
            const float y = ob2[(da + 1) * NNP + nn2];
            *(float2*)(outb + (size_t)nn2 * (NT * 3) + (size_t)(NT - CH) * 3 + da) =
                make_float2(x, y);
        }
    }
}

extern "C" void kernel_launch(void* const* d_in, const int* in_sizes, int n_in,
                              void* d_out, int out_size, void* d_ws, size_t ws_size,
                              hipStream_t stream) {
    const float* w         = (const float*)d_in[0];
    const float* ic        = (const float*)d_in[1];
    const float* v0        = (const float*)d_in[2];
    const float* i0        = (const float*)d_in[3];
    const float* s0        = (const float*)d_in[4];
    const float* mu        = (const float*)d_in[5];
    const float* sigma     = (const float*)d_in[6];
    const float* noise     = (const float*)d_in[7];
    const float* exp_draws = (const float*)d_in[8];
    float* out = (float*)d_out;

    (void)hipFuncSetAttribute((const void*)snn_scan_kernel,
                              hipFuncAttributeMaxDynamicSharedMemorySize,
                              LDS_BYTES);

    snn_scan_kernel<<<dim3(NS), dim3(192), LDS_BYTES, stream>>>(
        w, ic, v0, i0, s0, mu, sigma, noise, exp_draws, out);
}

// Round 20
// 569.567 us; speedup vs baseline: 1.0533x; 1.0533x over previous
//
#include <hip/hip_runtime.h>
#include <cmath>

#define NS 64
#define NN 128
#define NT 1000
#define CH 8                                // steps per obuf half-buffer
#define NNP 129                             // padded flush-row stride (bank-free)
#define WROWS 130                           // 128 rows of w + 2 zero rows
#define WL_DW (WROWS * NN)                  // 16640
#define OB_HALF (CH * 3 * NNP)              // 3096 dwords per half-buffer
#define OBUF_DW (2 * OB_HALF)               // 6192
#define LDS_BYTES ((WL_DW + OBUF_DW) * 4 + 32)   // 91360

// == npy_logaddexpf(x, 0), branch-free but bit-identical:
//   x>0: fmax=x, |x|=x  -> x + log1p(exp(-x)) ; x<0: 0 + log1p(exp(x)) ; x==0 -> LOGE2
__device__ __forceinline__ float softplus_np(float x) {
    float r = fmaxf(x, 0.0f) + log1pf(expf(-fabsf(x)));
    return (x == 0.0f) ? 0.693147180559945309f : r;
}

// Barrier WITHOUT the compiler's vmcnt(0) drain: LDS-visibility only.
__device__ __forceinline__ void sync_lds() {
    __builtin_amdgcn_sched_barrier(0);
    asm volatile("s_waitcnt lgkmcnt(0)" ::: "memory");
    __builtin_amdgcn_s_barrier();
    __builtin_amdgcn_sched_barrier(0);
}

__global__ __launch_bounds__(192) void snn_scan_kernel(
    const float* __restrict__ w,
    const float* __restrict__ ic,
    const float* __restrict__ v0,
    const float* __restrict__ i0,
    const float* __restrict__ s0,
    const float* __restrict__ mu,
    const float* __restrict__ sigma,
    const float* __restrict__ noise,      // [T, S, N, 2]
    const float* __restrict__ exp_draws,  // [T, S, N]
    float* __restrict__ out)              // [S, N, T, 3]
{
    #pragma clang fp contract(off)
    extern __shared__ float smem[];
    float* wl   = smem;                   // [130][128]: w rows + 2 zero rows
    float* obuf = smem + WL_DW;           // [2][CH*3][NNP] output staging (padded)
    unsigned long long* mslot =           // [2 parity][2 waves] spike masks
        (unsigned long long*)(smem + WL_DW + OBUF_DW);

    const int samp = blockIdx.x;
    const int tid  = threadIdx.x;
    const int wid  = tid >> 6;            // waves 0,1 = compute; wave 2 = flush
    const int l    = tid & 63;
    const int n    = (wid << 6) | l;      // neuron (waves 0,1): 1 neuron/lane

    if (tid < 128) {                      // stage w + zero rows (one-time)
        const float4* src = (const float4*)w;
        float4* dst = (float4*)wl;
        #pragma unroll
        for (int it = 0; it < 32; ++it)
            dst[it * 128 + tid] = src[it * 128 + tid];
        ((float2*)(wl + NN * NN))[tid] = make_float2(0.0f, 0.0f);
    }

    const float SQDT  = sqrtf(0.01f);     // 0x3DCCCCCD == np.sqrt(float32(0.01))
    const float DTf   = 0.01f;
    const float LOGE2 = 0.693147180559945309f;

    float* outb = out + (size_t)samp * NN * NT * 3;

    float mu1 = 0.f, negmu2 = 0.f, g00 = 0.f, g01 = 0.f, g10 = 0.f, g11 = 0.f;
    float icn = 0.f, v_ = 0.f, i_ = 0.f, s_ = 0.f, sp = 0.f;
    float2 nb0 = {}, nb1 = {}, nb2 = {}, nb3 = {}, nb4 = {}, nb5 = {}, nb6 = {}, nb7 = {};
    float  eb0 = 0, eb1 = 0, eb2 = 0, eb3 = 0, eb4 = 0, eb5 = 0, eb6 = 0, eb7 = 0;

    const float* nzb = noise + (size_t)samp * (NN * 2) + n * 2;   // + t*NS*NN*2
    const float* edb = exp_draws + (size_t)samp * NN + n;         // + t*NS*NN

    if (wid < 2) {
        __builtin_amdgcn_s_setprio(1);    // compute waves own the critical path
        mu1 = mu[0]; negmu2 = -mu[1];
        g00 = sigma[0]; g01 = sigma[1]; g10 = sigma[2]; g11 = sigma[3];
        icn = ic[n];
        v_ = v0[samp * NN + n];
        i_ = i0[samp * NN + n];
        s_ = s0[samp * NN + n];
        sp = softplus_np(v_);
        nb0 = *(const float2*)(nzb + 0ull * (NS * NN * 2)); eb0 = edb[0ull * (NS * NN)];
        nb1 = *(const float2*)(nzb + 1ull * (NS * NN * 2)); eb1 = edb[1ull * (NS * NN)];
        nb2 = *(const float2*)(nzb + 2ull * (NS * NN * 2)); eb2 = edb[2ull * (NS * NN)];
        nb3 = *(const float2*)(nzb + 3ull * (NS * NN * 2)); eb3 = edb[3ull * (NS * NN)];
        nb4 = *(const float2*)(nzb + 4ull * (NS * NN * 2)); eb4 = edb[4ull * (NS * NN)];
        nb5 = *(const float2*)(nzb + 5ull * (NS * NN * 2)); eb5 = edb[5ull * (NS * NN)];
        nb6 = *(const float2*)(nzb + 6ull * (NS * NN * 2)); eb6 = edb[6ull * (NS * NN)];
        nb7 = *(const float2*)(nzb + 7ull * (NS * NN * 2)); eb7 = edb[7ull * (NS * NN)];
    }
    sync_lds();                           // w + zero rows visible

    if (wid < 2) {
        // ---------------- compute waves ----------------
        auto STEP = [&](int k, int blk, float2& nb, float& eb) {
            #pragma clang fp contract(off)
            const int t = blk * CH + k;
            // --- pre-barrier: s-chain + spike-mask publish (depends on s,sp only)
            s_ = s_ + DTf * sp;
            const bool kk = (s_ >= 0.0f);
            const unsigned long long mym = __ballot(kk);
            if (l == 0) mslot[(k & 1) * 2 + wid] = mym;
            sync_lds();
            // --- post-barrier: drift + noise overlap the mask-read latency
            const float2 nz = nb;
            const float  ed = eb;
            const int tp = (t + 8) < NT ? (t + 8) : NT - 1;   // clamped prefetch
            nb = *(const float2*)(nzb + (size_t)tp * (NS * NN * 2));
            eb = edb[(size_t)tp * (NS * NN)];

            const float dw0 = nz.x * SQDT, dw1 = nz.y * SQDT;
            const float nv = (dw0 * g00) + (dw1 * g01);
            const float ni = (dw0 * g10) + (dw1 * g11);
            const float tt = (i_ + icn) - v_;
            const float vt = (v_ + DTf * (mu1 * tt)) + nv;
            const float it = (i_ + DTf * (negmu2 * i_)) + ni;
            const float spv = softplus_np(vt);   // speculative next-step intensity

            unsigned long long m0 = mslot[(k & 1) * 2 + 0];   // neurons 0..63
            unsigned long long m1 = mslot[(k & 1) * 2 + 1];   // neurons 64..127

            float a = 0.0f;
            if (m0 | m1) {                // wave-uniform skip of empty steps
                auto ext1 = [&]() -> int {    // ascending order: drain m0 then m1
                    const bool u0 = (m0 != 0);
                    const unsigned long long m = u0 ? m0 : m1;
                    const int b = m ? (int)__builtin_ctzll(m) : 99;
                    const int r = (b == 99) ? 128 : ((u0 ? 0 : 64) + b);
                    const unsigned long long m0n = m0 & (m0 - 1);
                    const unsigned long long m1n = m1 & (m1 - 1);
                    m0 = u0 ? m0n : m0;
                    m1 = u0 ? m1 : m1n;
                    return r;             // empty -> zero row 128 (+0.0 exact)
                };
                const int r1 = ext1(); const int r2 = ext1();
                const int r3 = ext1(); const int r4 = ext1();
                const float q1 = wl[r1 * NN + n];   // 4 independent ds_read_b32
                const float q2 = wl[r2 * NN + n];
                const float q3 = wl[r3 * NN + n];
                const float q4 = wl[r4 * NN + n];
                a = q1;  a += q2;  a += q3;  a += q4;   // ascending fp32 sum
                #pragma clang loop unroll(disable)
                while (m0 | m1) {                     // >=5 spikes: rare
                    const int r = ext1();
                    a += wl[r * NN + n];
                }
            }
            i_ = it + a;                  // unconditional add: bit-identical

            v_ = kk ? 0.0f : vt;
            s_ = kk ? -ed : s_;
            sp = kk ? LOGE2 : spv;

            float* row = obuf + (blk & 1) * OB_HALF + (k * 3) * NNP + n;
            row[0 * NNP] = v_;            // padded rows: flush side bank-free
            row[1 * NNP] = i_;
            row[2 * NNP] = s_;
        };

        #pragma clang loop unroll(disable)
        for (int blk = 0; blk < NT / CH; ++blk) {
            STEP(0, blk, nb0, eb0);
            STEP(1, blk, nb1, eb1);
            STEP(2, blk, nb2, eb2);
            STEP(3, blk, nb3, eb3);
            STEP(4, blk, nb4, eb4);
            STEP(5, blk, nb5, eb5);
            STEP(6, blk, nb6, eb6);
            STEP(7, blk, nb7, eb7);
        }
    } else {
        // ---------------- flush wave ----------------
        auto flush3 = [&](int h, int tb0, int kk) {
            // half layout [24][NNP]; neuron nn2's 24 dwords are column nn2.
            // stride 129: adjacent neuron-groups alternate bank parity -> free
            const float* ob2 = obuf + h * OB_HALF;
            #pragma unroll
            for (int j = 3 * kk; j < 3 * kk + 3; ++j) {
                const int f = j * 64 + l;        // float2 slot 0..1535
                const int nn2 = f / 12;          // neuron
                const int da = 2 * (f - nn2 * 12);
                const float x = ob2[(da    ) * NNP + nn2];
                const float y = ob2[(da + 1) * NNP + nn2];
                *(float2*)(outb + (size_t)nn2 * (NT * 3) + (size_t)tb0 * 3 + da) =
                    make_float2(x, y);
            }
        };
        #pragma clang loop unroll(disable)
        for (int blk = 0; blk < NT / CH; ++blk) {
            #pragma clang loop unroll(disable)
            for (int k = 0; k < CH; ++k) {
                sync_lds();               // match compute waves' per-step barrier
                if (blk > 0) flush3((blk - 1) & 1, (blk - 1) * CH, k);
            }
        }
    }

    // tail: the last CH steps' obuf writes happen after barrier (124,7);
    // all waves must cross one more barrier before the tail flush reads them.
    sync_lds();
    if (wid == 2) {
        const float* ob2 = obuf + ((NT / CH - 1) & 1) * OB_HALF;   // half 0
        #pragma unroll
        for (int j = 0; j < 24; ++j) {
            const int f = j * 64 + l;
            const int nn2 = f / 12;
            const int da = 2 * (f - nn2 * 12);
            const float x = ob2[(da    ) * NNP + nn2];
            const float y = ob2[(da + 1) * NNP + nn2];
            *(float2*)(outb + (size_t)nn2 * (NT * 3) + (size_t)(NT - CH) * 3 + da) =
                make_float2(x, y);
        }
    }
}

extern "C" void kernel_launch(void* const* d_in, const int* in_sizes, int n_in,
                              void* d_out, int out_size, void* d_ws, size_t ws_size,
                              hipStream_t stream) {
    const float* w         = (const float*)d_in[0];
    const float* ic        = (const float*)d_in[1];
    const float* v0        = (const float*)d_in[2];
    const float* i0        = (const float*)d_in[3];
    const float* s0        = (const float*)d_in[4];
    const float* mu        = (const float*)d_in[5];
    const float* sigma     = (const float*)d_in[6];
    const float* noise     = (const float*)d_in[7];
    const float* exp_draws = (const float*)d_in[8];
    float* out = (float*)d_out;

    (void)hipFuncSetAttribute((const void*)snn_scan_kernel,
                              hipFuncAttributeMaxDynamicSharedMemorySize,
                              LDS_BYTES);

    snn_scan_kernel<<<dim3(NS), dim3(192), LDS_BYTES, stream>>>(
        w, ic, v0, i0, s0, mu, sigma, noise, exp_draws, out);
}